// Round 6
// baseline (114.300 us; speedup 1.0000x reference)
//
#include <hip/hip_runtime.h>
#include <hip/hip_bf16.h>

typedef unsigned short u16;
typedef __attribute__((ext_vector_type(8))) short bhalf8;
typedef __attribute__((ext_vector_type(4))) float fx4;

struct __align__(8) US4 { u16 v[4]; };
struct __align__(16) US8 { u16 v[8]; };

__device__ __forceinline__ u16 f2bf(float x) {
  union { float f; unsigned int u; } c; c.f = x;
  unsigned int r = c.u + 0x7FFFu + ((c.u >> 16) & 1u);
  return (u16)(r >> 16);
}

__device__ __forceinline__ u16 f2bf_hw(float x) {
  union { __hip_bfloat16 h; u16 u; } c;
  c.h = __float2bfloat16(x);
  return c.u;
}

__device__ __forceinline__ void gload16(const void* g, void* l) {
  __builtin_amdgcn_global_load_lds((const __attribute__((address_space(1))) void*)g,
                                   (__attribute__((address_space(3))) void*)l,
                                   16, 0, 0);
}

#define MFMA16(a, b, c) __builtin_amdgcn_mfma_f32_16x16x32_bf16((a), (b), (c), 0, 0, 0)

// transpose [R][C] f32 -> [C][R] bf16, 64x64 tiles.
// remap!=0: output rows >=512 get per-head K/V interleave:
//   K col c in [512,1024)  -> 512 + h*128 +      (c-512)%64
//   V col c in [1024,1536) -> 512 + h*128 + 64 + (c-1024)%64
__global__ void k_transpose(const float* __restrict__ in, u16* __restrict__ out,
                            int R, int C, int rtiles, int remap) {
  __shared__ float tile[64][65];
  const int bx = blockIdx.x;
  const int rt = bx % rtiles, ct = bx / rtiles;
  const int r0 = rt * 64, c0 = ct * 64;
  const int t = threadIdx.x;
  #pragma unroll
  for (int i = 0; i < 16; ++i) {
    int e = i * 256 + t;
    int rr = e >> 6, cc = e & 63;
    tile[rr][cc] = in[(r0 + rr) * C + c0 + cc];
  }
  __syncthreads();
  #pragma unroll
  for (int i = 0; i < 16; ++i) {
    int e = i * 256 + t;
    int rr = e >> 6, cc = e & 63;
    int orow = c0 + rr;
    if (remap && orow >= 512) {
      int region = (orow - 512) >> 9;       // 0=K, 1=V
      int within = (orow - 512) & 511;
      int h = within >> 6;
      orow = 512 + h * 128 + region * 64 + (within & 63);
    }
    out[orow * R + r0 + cc] = f2bf(tile[cc][rr]);
  }
}

// ---------------- 128x128 GEMM mainloop, A read from f32 global (fused convert) ----------------
// A: reg-staged (8x float4/thread) -> cvt bf16 -> ds_write_b128 into swizzled LDS.
// B: global_load_lds with pre-swizzled source (bf16, row stride 1024B).
__device__ __forceinline__ void gemm_core_f32A(const float* __restrict__ Ax,
                                               const char* __restrict__ Bb,
                                               char* As, char* Bs, fx4 acc[4][4]) {
  const int t = threadIdx.x;
  const int w = t >> 6, l = t & 63;
  const int wm = w >> 1, wn = w & 1;
  const int arow = t >> 1, ah = t & 1;
  const float4* asrc = (const float4*)(Ax + arow * 512 + ah * 32);
  char* adst = As + arow * 128;
  const int aswz = (arow & 7) << 4;
  #pragma unroll 1
  for (int kt = 0; kt < 8; ++kt) {
    __syncthreads();
    // A: 32 f32 for this thread's (row, 32-col half)
    float4 av[8];
    #pragma unroll
    for (int q = 0; q < 8; ++q) av[q] = asrc[kt * 16 + q];
    // B: 16KB via global_load_lds
    const int kb = kt * 128;
    #pragma unroll
    for (int j = 0; j < 4; ++j) {
      int off = ((j * 4 + w) * 64 + l) * 16;
      int row = off >> 7;
      int scol = (off & 127) ^ ((row & 7) << 4);
      gload16(Bb + row * 1024 + kb + scol, Bs + off);
    }
    // convert + swizzled ds_write (matches read-side swizzle)
    #pragma unroll
    for (int q = 0; q < 4; ++q) {
      US8 p;
      p.v[0] = f2bf_hw(av[2 * q].x);     p.v[1] = f2bf_hw(av[2 * q].y);
      p.v[2] = f2bf_hw(av[2 * q].z);     p.v[3] = f2bf_hw(av[2 * q].w);
      p.v[4] = f2bf_hw(av[2 * q + 1].x); p.v[5] = f2bf_hw(av[2 * q + 1].y);
      p.v[6] = f2bf_hw(av[2 * q + 1].z); p.v[7] = f2bf_hw(av[2 * q + 1].w);
      *(US8*)(adst + ((ah * 64 + q * 16) ^ aswz)) = p;
    }
    asm volatile("s_waitcnt vmcnt(0)" ::: "memory");
    __syncthreads();
    #pragma unroll
    for (int ks = 0; ks < 2; ++ks) {
      bhalf8 af[4], bfv[4];
      const int kbyte = ks * 64 + ((l >> 4) * 16);
      #pragma unroll
      for (int f = 0; f < 4; ++f) {
        int ra = wm * 64 + f * 16 + (l & 15);
        af[f] = *(const bhalf8*)(As + ra * 128 + (kbyte ^ ((ra & 7) << 4)));
        int rb = wn * 64 + f * 16 + (l & 15);
        bfv[f] = *(const bhalf8*)(Bs + rb * 128 + (kbyte ^ ((rb & 7) << 4)));
      }
      #pragma unroll
      for (int fm = 0; fm < 4; ++fm)
        #pragma unroll
        for (int fn = 0; fn < 4; ++fn)
          acc[fm][fn] = MFMA16(af[fm], bfv[fn], acc[fm][fn]);
    }
  }
}

// ---------------- original 128x128 core (both operands bf16, gload_lds) ----------------
__device__ __forceinline__ void gemm_core(const char* Ab, const char* Bb,
                                          char* As, char* Bs, fx4 acc[4][4]) {
  const int t = threadIdx.x;
  const int w = t >> 6, l = t & 63;
  const int wm = w >> 1, wn = w & 1;
  #pragma unroll 1
  for (int kt = 0; kt < 8; ++kt) {
    __syncthreads();
    const int kb = kt * 128;
    #pragma unroll
    for (int j = 0; j < 4; ++j) {
      int off = ((j * 4 + w) * 64 + l) * 16;
      int row = off >> 7;
      int colb = off & 127;
      int scol = colb ^ ((row & 7) << 4);
      gload16(Ab + row * 1024 + kb + scol, As + off);
      gload16(Bb + row * 1024 + kb + scol, Bs + off);
    }
    asm volatile("s_waitcnt vmcnt(0)" ::: "memory");
    __syncthreads();
    #pragma unroll
    for (int ks = 0; ks < 2; ++ks) {
      bhalf8 af[4], bfv[4];
      const int kbyte = ks * 64 + ((l >> 4) * 16);
      #pragma unroll
      for (int f = 0; f < 4; ++f) {
        int ra = wm * 64 + f * 16 + (l & 15);
        af[f] = *(const bhalf8*)(As + ra * 128 + (kbyte ^ ((ra & 7) << 4)));
        int rb = wn * 64 + f * 16 + (l & 15);
        bfv[f] = *(const bhalf8*)(Bs + rb * 128 + (kbyte ^ ((rb & 7) << 4)));
      }
      #pragma unroll
      for (int fm = 0; fm < 4; ++fm)
        #pragma unroll
        for (int fn = 0; fn < 4; ++fn)
          acc[fm][fn] = MFMA16(af[fm], bfv[fn], acc[fm][fn]);
    }
  }
}

// ---------------- K1: qkv GEMM (x f32 direct) + fused q-softmax / k-exp / ctx partials ----------------
// grid 1536 = 128 M-tiles x 12 N-tiles; XCD-swizzled. tN 0..3: Q. tN 4..11: head h=tN-4 (K|V halves)
__global__ __launch_bounds__(256, 2)
void k_qkv_gemm(const float* __restrict__ x, const char* __restrict__ wqT,
                u16* __restrict__ qhat, float* __restrict__ ctx_part,
                float* __restrict__ z_part) {
  __shared__ __align__(16) char lds[32768];
  const int bid = blockIdx.x;
  const int nb = (bid & 7) * 192 + (bid >> 3);   // XCD-contiguous chunks
  const int tM = nb & 127, tN = nb >> 7;
  fx4 acc[4][4];
  const fx4 z4 = {0.f, 0.f, 0.f, 0.f};
  #pragma unroll
  for (int i = 0; i < 4; ++i)
    #pragma unroll
    for (int j = 0; j < 4; ++j) acc[i][j] = z4;

  gemm_core_f32A(x + tM * 65536, wqT + tN * 131072, lds, lds + 16384, acc);

  const int t = threadIdx.x, w = t >> 6, l = t & 63;
  const int wm = w >> 1, wn = w & 1;
  const int m0 = tM * 128 + wm * 64;
  const int c0 = tN * 128 + wn * 64;

  if (tN < 4) {
    // q: softmax over the 64 head-dim cols (exactly this wave's col span)
    #pragma unroll
    for (int fm = 0; fm < 4; ++fm) {
      #pragma unroll
      for (int fn = 0; fn < 4; ++fn)
        #pragma unroll
        for (int r = 0; r < 4; ++r)
          acc[fm][fn][r] = __expf(acc[fm][fn][r]);
      fx4 s = acc[fm][0] + acc[fm][1] + acc[fm][2] + acc[fm][3];
      fx4 inv;
      #pragma unroll
      for (int r = 0; r < 4; ++r) {
        float sv = s[r];
        sv += __shfl_xor(sv, 1, 64);
        sv += __shfl_xor(sv, 2, 64);
        sv += __shfl_xor(sv, 4, 64);
        sv += __shfl_xor(sv, 8, 64);
        inv[r] = 1.0f / sv;
      }
      #pragma unroll
      for (int fn = 0; fn < 4; ++fn)
        #pragma unroll
        for (int r = 0; r < 4; ++r) {
          int m = m0 + fm * 16 + ((l >> 4) * 4) + r;
          int c = c0 + fn * 16 + (l & 15);
          qhat[m * 512 + c] = f2bf(acc[fm][fn][r] * inv[r]);
        }
    }
  } else {
    const int h = tN - 4;
    const int b = tM >> 5;
    const int mt = tM & 31;
    const int bh = b * 8 + h;
    char* ktb = lds;            // 64 d-rows x 128 n bf16, swizzled (16KB)
    char* vtb = lds + 16384;
    __syncthreads();            // staging LDS free now
    {
      char* dstb = (wn == 0) ? ktb : vtb;
      const bool isK = (wn == 0);
      #pragma unroll
      for (int fm = 0; fm < 4; ++fm)
        #pragma unroll
        for (int fn = 0; fn < 4; ++fn) {
          int d = fn * 16 + (l & 15);
          int n0 = wm * 64 + fm * 16 + ((l >> 4) * 4);
          US4 p;
          #pragma unroll
          for (int r = 0; r < 4; ++r) {
            float v = acc[fm][fn][r];
            if (isK) { float tt = v > 0.f ? v + 1.f : __expf(v); v = __expf(tt); }
            p.v[r] = f2bf(v);
          }
          *(US4*)(dstb + d * 256 + ((2 * n0) ^ ((d & 7) << 4))) = p;
        }
    }
    __syncthreads();
    // ctx[d][e] = sum_n khat[d][n]*v[e][n]; wave w owns d-rows [w*16, w*16+16)
    fx4 cacc[4]; fx4 zacc = z4;
    #pragma unroll
    for (int fn = 0; fn < 4; ++fn) cacc[fn] = z4;
    bhalf8 ones;
    #pragma unroll
    for (int i = 0; i < 8; ++i) ones[i] = (short)0x3F80;  // bf16 1.0
    #pragma unroll
    for (int kk = 0; kk < 4; ++kk) {
      int nbyte = kk * 64 + ((l >> 4) * 16);
      int d = w * 16 + (l & 15);
      bhalf8 a = *(const bhalf8*)(ktb + d * 256 + (nbyte ^ ((d & 7) << 4)));
      #pragma unroll
      for (int fn = 0; fn < 4; ++fn) {
        int e = fn * 16 + (l & 15);
        bhalf8 bv = *(const bhalf8*)(vtb + e * 256 + (nbyte ^ ((e & 7) << 4)));
        cacc[fn] = MFMA16(a, bv, cacc[fn]);
      }
      zacc = MFMA16(a, ones, zacc);
    }
    float* cp = ctx_part + (bh * 32 + mt) * 4096;
    #pragma unroll
    for (int fn = 0; fn < 4; ++fn)
      #pragma unroll
      for (int r = 0; r < 4; ++r) {
        int d = w * 16 + ((l >> 4) * 4) + r;
        int e = fn * 16 + (l & 15);
        cp[d * 64 + e] = cacc[fn][r];
      }
    if ((l & 15) == 0) {
      #pragma unroll
      for (int r = 0; r < 4; ++r)
        z_part[(bh * 32 + mt) * 64 + w * 16 + ((l >> 4) * 4) + r] = zacc[r];
    }
  }
}

// ---------------- K2: reduce ctx partials over the 32 M-blocks ----------------
__global__ __launch_bounds__(256)
void k_reduce(const float* __restrict__ ctx_part, float* __restrict__ ctx32) {
  const int bx = blockIdx.x;    // 512 = 32 bh x 16 slices
  const int bh = bx >> 4;
  const int idx = (bx & 15) * 256 + threadIdx.x;
  float s = 0.f;
  #pragma unroll
  for (int mt = 0; mt < 32; ++mt)
    s += ctx_part[(bh * 32 + mt) * 4096 + idx];
  ctx32[bh * 4096 + idx] = s;
}

// ---------------- K3: W2T[b][c][hd] = sum_e (ctx[d][e]/Z[d]) * wp[h*64+e][c]  (bf16 MFMA) ----------------
__global__ __launch_bounds__(256, 1)
void k_w2(const float* __restrict__ ctx32, const float* __restrict__ z_part,
          const u16* __restrict__ wpT, u16* __restrict__ W2T) {
  const int bh = blockIdx.x;            // 32
  const int b = bh >> 3, h = bh & 7;
  __shared__ float zinv[64];
  __shared__ __align__(16) u16 alds[64][72];
  const int t = threadIdx.x;
  if (t < 64) {
    float zs = 0.f;
    #pragma unroll
    for (int mt = 0; mt < 32; ++mt) zs += z_part[(bh * 32 + mt) * 64 + t];
    zinv[t] = 1.0f / zs;
  }
  __syncthreads();
  #pragma unroll
  for (int i = 0; i < 16; ++i) {
    int idx = i * 256 + t;
    int d = idx >> 6, e = idx & 63;
    alds[d][e] = f2bf(ctx32[bh * 4096 + idx] * zinv[d]);
  }
  __syncthreads();
  const int w = t >> 6, l = t & 63;
  fx4 acc[4][8];
  const fx4 z4 = {0.f, 0.f, 0.f, 0.f};
  #pragma unroll
  for (int i = 0; i < 4; ++i)
    #pragma unroll
    for (int j = 0; j < 8; ++j) acc[i][j] = z4;
  #pragma unroll
  for (int ks = 0; ks < 2; ++ks) {
    bhalf8 af[4];
    #pragma unroll
    for (int fm = 0; fm < 4; ++fm) {
      int row = fm * 16 + (l & 15);
      af[fm] = *(const bhalf8*)((const char*)alds + row * 144 + ks * 64 + ((l >> 4) * 16));
    }
    #pragma unroll
    for (int fn = 0; fn < 8; ++fn) {
      int c = w * 128 + fn * 16 + (l & 15);
      bhalf8 bv = *(const bhalf8*)(wpT + c * 512 + h * 64 + ks * 32 + ((l >> 4) * 8));
      #pragma unroll
      for (int fm = 0; fm < 4; ++fm)
        acc[fm][fn] = MFMA16(af[fm], bv, acc[fm][fn]);
    }
  }
  #pragma unroll
  for (int fm = 0; fm < 4; ++fm)
    #pragma unroll
    for (int fn = 0; fn < 8; ++fn) {
      int c = w * 128 + fn * 16 + (l & 15);
      int d0 = fm * 16 + ((l >> 4) * 4);
      US4 p;
      #pragma unroll
      for (int r = 0; r < 4; ++r) p.v[r] = f2bf(acc[fm][fn][r]);
      *(US4*)(W2T + (b * 512 + c) * 512 + h * 64 + d0) = p;
    }
}

// ---------------- K4: final GEMM  out = qhat @ W2_b + bias ----------------
// grid 512 = 128 M-tiles x 4 N-tiles; XCD-swizzled
__global__ __launch_bounds__(256, 2)
void k_out_gemm(const char* __restrict__ qhat, const char* __restrict__ W2T,
                const float* __restrict__ bproj, float* __restrict__ outp) {
  __shared__ __align__(16) char lds[32768];
  const int bid = blockIdx.x;
  const int nb = (bid & 7) * 64 + (bid >> 3);
  const int tM = nb & 127, tN = nb >> 7;
  const int b = tM >> 5;
  fx4 acc[4][4];
  const fx4 z4 = {0.f, 0.f, 0.f, 0.f};
  #pragma unroll
  for (int i = 0; i < 4; ++i)
    #pragma unroll
    for (int j = 0; j < 4; ++j) acc[i][j] = z4;

  gemm_core(qhat + tM * 131072, W2T + b * 524288 + tN * 131072, lds, lds + 16384, acc);

  const int t = threadIdx.x, w = t >> 6, l = t & 63;
  const int wm = w >> 1, wn = w & 1;
  const int m0 = tM * 128 + wm * 64;
  const int c0 = tN * 128 + wn * 64;
  #pragma unroll
  for (int fm = 0; fm < 4; ++fm)
    #pragma unroll
    for (int fn = 0; fn < 4; ++fn) {
      int c = c0 + fn * 16 + (l & 15);
      float bp = bproj[c];
      #pragma unroll
      for (int r = 0; r < 4; ++r) {
        int m = m0 + fm * 16 + ((l >> 4) * 4) + r;
        outp[m * 512 + c] = acc[fm][fn][r] + bp;
      }
    }
}

extern "C" void kernel_launch(void* const* d_in, const int* in_sizes, int n_in,
                              void* d_out, int out_size, void* d_ws, size_t ws_size,
                              hipStream_t stream) {
  (void)in_sizes; (void)n_in; (void)out_size;
  const float* x     = (const float*)d_in[0];
  const float* wqkv  = (const float*)d_in[1];
  const float* wproj = (const float*)d_in[2];
  const float* bproj = (const float*)d_in[3];
  float* outp = (float*)d_out;
  char* ws = (char*)d_ws;

  char* wqT  = ws;                 // 1536*512*2        =  1,572,864
  char* wpT  = ws + 1572864;       // 512*512*2         =    524,288
  char* qhat = ws + 2097152;       // 16384*512*2       = 16,777,216
  char* ctxp = ws + 18874368;      // 32*32*4096*4      = 16,777,216
  char* zp   = ws + 35651584;      // 32*32*64*4        =    262,144
  char* ctx32= ws + 35913728;      // 32*4096*4         =    524,288
  char* w2t  = ws + 36438016;      // 4*512*512*2       =  2,097,152  (end 38,535,168)
  if (ws_size < 38535168) return;

  k_transpose<<<192, 256, 0, stream>>>(wqkv, (u16*)wqT, 512, 1536, 8, 1);
  k_transpose<<<64, 256, 0, stream>>>(wproj, (u16*)wpT, 512, 512, 8, 0);
  k_qkv_gemm<<<1536, 256, 0, stream>>>(x, wqT, (u16*)qhat, (float*)ctxp, (float*)zp);
  k_reduce<<<512, 256, 0, stream>>>((const float*)ctxp, (float*)ctx32);
  k_w2<<<32, 256, 0, stream>>>((const float*)ctx32, (const float*)zp, (const u16*)wpT, (u16*)w2t);
  k_out_gemm<<<512, 256, 0, stream>>>(qhat, w2t, bproj, outp);
}

// Round 7
// 89.719 us; speedup vs baseline: 1.2740x; 1.2740x over previous
//
#include <hip/hip_runtime.h>
#include <hip/hip_bf16.h>

typedef unsigned short u16;
typedef __attribute__((ext_vector_type(8))) short bhalf8;
typedef __attribute__((ext_vector_type(4))) float fx4;

struct __align__(8) US4 { u16 v[4]; };

__device__ __forceinline__ u16 f2bf(float x) {
  union { float f; unsigned int u; } c; c.f = x;
  unsigned int r = c.u + 0x7FFFu + ((c.u >> 16) & 1u);
  return (u16)(r >> 16);
}

__device__ __forceinline__ void gload16(const void* g, void* l) {
  __builtin_amdgcn_global_load_lds((const __attribute__((address_space(1))) void*)g,
                                   (__attribute__((address_space(3))) void*)l,
                                   16, 0, 0);
}

#define MFMA16(a, b, c) __builtin_amdgcn_mfma_f32_16x16x32_bf16((a), (b), (c), 0, 0, 0)

// ---------------- input conversion ----------------
__global__ void k_conv(const float* __restrict__ in, u16* __restrict__ out, int n4) {
  int i = blockIdx.x * 256 + threadIdx.x;
  if (i < n4) {
    float4 v = ((const float4*)in)[i];
    US4 o;
    o.v[0] = f2bf(v.x); o.v[1] = f2bf(v.y); o.v[2] = f2bf(v.z); o.v[3] = f2bf(v.w);
    ((US4*)out)[i] = o;
  }
}

// transpose [R][C] f32 -> [C][R] bf16, 64x64 tiles.
// remap!=0: output rows >=512 get per-head K/V interleave:
//   K col c in [512,1024)  -> 512 + h*128 +      (c-512)%64
//   V col c in [1024,1536) -> 512 + h*128 + 64 + (c-1024)%64
__global__ void k_transpose(const float* __restrict__ in, u16* __restrict__ out,
                            int R, int C, int rtiles, int remap) {
  __shared__ float tile[64][65];
  const int bx = blockIdx.x;
  const int rt = bx % rtiles, ct = bx / rtiles;
  const int r0 = rt * 64, c0 = ct * 64;
  const int t = threadIdx.x;
  #pragma unroll
  for (int i = 0; i < 16; ++i) {
    int e = i * 256 + t;
    int rr = e >> 6, cc = e & 63;
    tile[rr][cc] = in[(r0 + rr) * C + c0 + cc];
  }
  __syncthreads();
  #pragma unroll
  for (int i = 0; i < 16; ++i) {
    int e = i * 256 + t;
    int rr = e >> 6, cc = e & 63;
    int orow = c0 + rr;
    if (remap && orow >= 512) {
      int region = (orow - 512) >> 9;       // 0=K, 1=V
      int within = (orow - 512) & 511;
      int h = within >> 6;
      orow = 512 + h * 128 + region * 64 + (within & 63);
    }
    out[orow * R + r0 + cc] = f2bf(tile[cc][rr]);
  }
}

// ---------------- shared 128x128 GEMM mainloop (K=512, both operand row strides = 1024B) ----------------
__device__ __forceinline__ void gemm_core(const char* Ab, const char* Bb,
                                          char* As, char* Bs, fx4 acc[4][4]) {
  const int t = threadIdx.x;
  const int w = t >> 6, l = t & 63;
  const int wm = w >> 1, wn = w & 1;
  #pragma unroll 1
  for (int kt = 0; kt < 8; ++kt) {
    __syncthreads();
    const int kb = kt * 128;
    #pragma unroll
    for (int j = 0; j < 4; ++j) {
      int off = ((j * 4 + w) * 64 + l) * 16;     // byte offset in 16KB tile
      int row = off >> 7;
      int colb = off & 127;
      int scol = colb ^ ((row & 7) << 4);        // pre-swizzled global source
      gload16(Ab + row * 1024 + kb + scol, As + off);
      gload16(Bb + row * 1024 + kb + scol, Bs + off);
    }
    asm volatile("s_waitcnt vmcnt(0)" ::: "memory");
    __syncthreads();
    #pragma unroll
    for (int ks = 0; ks < 2; ++ks) {
      bhalf8 af[4], bfv[4];
      const int kbyte = ks * 64 + ((l >> 4) * 16);
      #pragma unroll
      for (int f = 0; f < 4; ++f) {
        int ra = wm * 64 + f * 16 + (l & 15);
        af[f] = *(const bhalf8*)(As + ra * 128 + (kbyte ^ ((ra & 7) << 4)));
        int rb = wn * 64 + f * 16 + (l & 15);
        bfv[f] = *(const bhalf8*)(Bs + rb * 128 + (kbyte ^ ((rb & 7) << 4)));
      }
      #pragma unroll
      for (int fm = 0; fm < 4; ++fm)
        #pragma unroll
        for (int fn = 0; fn < 4; ++fn)
          acc[fm][fn] = MFMA16(af[fm], bfv[fn], acc[fm][fn]);
    }
  }
}

// ---------------- K1: qkv GEMM + fused q-softmax / k-exp / per-block context partials ----------------
// tN 0..3: Q cols. tN 4..11: head h=tN-4, tile cols 0..63 = K-head-h, 64..127 = V-head-h
__global__ __launch_bounds__(256, 2)
void k_qkv_gemm(const char* __restrict__ xb, const char* __restrict__ wqT,
                u16* __restrict__ qhat, float* __restrict__ ctx_part,
                float* __restrict__ z_part) {
  __shared__ __align__(16) char lds[32768];
  const int bx = blockIdx.x;
  const int tM = bx & 127, tN = bx >> 7;  // 128 M-tiles, 12 N-tiles
  fx4 acc[4][4];
  const fx4 z4 = {0.f, 0.f, 0.f, 0.f};
  #pragma unroll
  for (int i = 0; i < 4; ++i)
    #pragma unroll
    for (int j = 0; j < 4; ++j) acc[i][j] = z4;

  gemm_core(xb + tM * 131072, wqT + tN * 131072, lds, lds + 16384, acc);

  const int t = threadIdx.x, w = t >> 6, l = t & 63;
  const int wm = w >> 1, wn = w & 1;
  const int m0 = tM * 128 + wm * 64;
  const int c0 = tN * 128 + wn * 64;

  if (tN < 4) {
    // q: softmax over the 64 head-dim cols (exactly this wave's col span)
    #pragma unroll
    for (int fm = 0; fm < 4; ++fm) {
      #pragma unroll
      for (int fn = 0; fn < 4; ++fn)
        #pragma unroll
        for (int r = 0; r < 4; ++r)
          acc[fm][fn][r] = __expf(acc[fm][fn][r]);
      fx4 s = acc[fm][0] + acc[fm][1] + acc[fm][2] + acc[fm][3];
      fx4 inv;
      #pragma unroll
      for (int r = 0; r < 4; ++r) {
        float sv = s[r];
        sv += __shfl_xor(sv, 1, 64);
        sv += __shfl_xor(sv, 2, 64);
        sv += __shfl_xor(sv, 4, 64);
        sv += __shfl_xor(sv, 8, 64);
        inv[r] = 1.0f / sv;
      }
      #pragma unroll
      for (int fn = 0; fn < 4; ++fn)
        #pragma unroll
        for (int r = 0; r < 4; ++r) {
          int m = m0 + fm * 16 + ((l >> 4) * 4) + r;
          int c = c0 + fn * 16 + (l & 15);
          qhat[m * 512 + c] = f2bf(acc[fm][fn][r] * inv[r]);
        }
    }
  } else {
    const int h = tN - 4;
    const int b = tM >> 5;
    const int mt = tM & 31;
    const int bh = b * 8 + h;
    char* ktb = lds;            // 64 x 128 bf16, swizzled, 16KB
    char* vtb = lds + 16384;    // 64 x 128 bf16, swizzled, 16KB
    __syncthreads();            // staging LDS free now
    {
      char* dstb = (wn == 0) ? ktb : vtb;
      const bool isK = (wn == 0);
      #pragma unroll
      for (int fm = 0; fm < 4; ++fm)
        #pragma unroll
        for (int fn = 0; fn < 4; ++fn) {
          int d = fn * 16 + (l & 15);
          int n0 = wm * 64 + fm * 16 + ((l >> 4) * 4);
          US4 p;
          #pragma unroll
          for (int r = 0; r < 4; ++r) {
            float v = acc[fm][fn][r];
            if (isK) { float tt = v > 0.f ? v + 1.f : __expf(v); v = __expf(tt); }
            p.v[r] = f2bf(v);
          }
          *(US4*)(dstb + d * 256 + ((2 * n0) ^ ((d & 7) << 4))) = p;
        }
    }
    __syncthreads();
    // ctx[d][e] += sum_n khat[n][d]*v[n][e]; wave w owns d-rows [w*16, w*16+16)
    fx4 cacc[4]; fx4 zacc = z4;
    #pragma unroll
    for (int fn = 0; fn < 4; ++fn) cacc[fn] = z4;
    bhalf8 ones;
    #pragma unroll
    for (int i = 0; i < 8; ++i) ones[i] = (short)0x3F80;  // bf16 1.0
    #pragma unroll
    for (int kk = 0; kk < 4; ++kk) {
      int nbyte = kk * 64 + ((l >> 4) * 16);
      int d = w * 16 + (l & 15);
      bhalf8 a = *(const bhalf8*)(ktb + d * 256 + (nbyte ^ ((d & 7) << 4)));
      #pragma unroll
      for (int fn = 0; fn < 4; ++fn) {
        int e = fn * 16 + (l & 15);
        bhalf8 bv = *(const bhalf8*)(vtb + e * 256 + (nbyte ^ ((e & 7) << 4)));
        cacc[fn] = MFMA16(a, bv, cacc[fn]);
      }
      zacc = MFMA16(a, ones, zacc);
    }
    float* cp = ctx_part + (bh * 32 + mt) * 4096;
    #pragma unroll
    for (int fn = 0; fn < 4; ++fn)
      #pragma unroll
      for (int r = 0; r < 4; ++r) {
        int d = w * 16 + ((l >> 4) * 4) + r;
        int e = fn * 16 + (l & 15);
        cp[d * 64 + e] = cacc[fn][r];
      }
    if ((l & 15) == 0) {
      #pragma unroll
      for (int r = 0; r < 4; ++r)
        z_part[(bh * 32 + mt) * 64 + w * 16 + ((l >> 4) * 4) + r] = zacc[r];
    }
  }
}

// ---------------- K2: W2T[b][c][hd] = sum_e (ctx[d][e]/Z[d]) * wp[h*64+e][c]  (bf16 MFMA) ----------------
// fused: reduces the 32 ctx/z partials directly (replaces the old k_reduce kernel)
__global__ __launch_bounds__(256, 1)
void k_w2(const float* __restrict__ ctx_part, const float* __restrict__ z_part,
          const u16* __restrict__ wpT, u16* __restrict__ W2T) {
  const int bh = blockIdx.x;            // 32
  const int b = bh >> 3, h = bh & 7;
  __shared__ float zinv[64];
  __shared__ __align__(16) u16 alds[64][72];
  const int t = threadIdx.x;
  if (t < 64) {
    float zs = 0.f;
    #pragma unroll
    for (int mt = 0; mt < 32; ++mt) zs += z_part[(bh * 32 + mt) * 64 + t];
    zinv[t] = 1.0f / zs;
  }
  __syncthreads();
  #pragma unroll 1
  for (int i = 0; i < 16; ++i) {
    int idx = i * 256 + t;
    int d = idx >> 6, e = idx & 63;
    float s = 0.f;
    #pragma unroll
    for (int mt = 0; mt < 32; ++mt)
      s += ctx_part[(bh * 32 + mt) * 4096 + idx];
    alds[d][e] = f2bf(s * zinv[d]);
  }
  __syncthreads();
  const int w = t >> 6, l = t & 63;
  fx4 acc[4][8];
  const fx4 z4 = {0.f, 0.f, 0.f, 0.f};
  #pragma unroll
  for (int i = 0; i < 4; ++i)
    #pragma unroll
    for (int j = 0; j < 8; ++j) acc[i][j] = z4;
  #pragma unroll
  for (int ks = 0; ks < 2; ++ks) {
    bhalf8 af[4];
    #pragma unroll
    for (int fm = 0; fm < 4; ++fm) {
      int row = fm * 16 + (l & 15);
      af[fm] = *(const bhalf8*)((const char*)alds + row * 144 + ks * 64 + ((l >> 4) * 16));
    }
    #pragma unroll
    for (int fn = 0; fn < 8; ++fn) {
      int c = w * 128 + fn * 16 + (l & 15);
      bhalf8 bv = *(const bhalf8*)(wpT + c * 512 + h * 64 + ks * 32 + ((l >> 4) * 8));
      #pragma unroll
      for (int fm = 0; fm < 4; ++fm)
        acc[fm][fn] = MFMA16(af[fm], bv, acc[fm][fn]);
    }
  }
  #pragma unroll
  for (int fm = 0; fm < 4; ++fm)
    #pragma unroll
    for (int fn = 0; fn < 8; ++fn) {
      int c = w * 128 + fn * 16 + (l & 15);
      int d0 = fm * 16 + ((l >> 4) * 4);
      US4 p;
      #pragma unroll
      for (int r = 0; r < 4; ++r) p.v[r] = f2bf(acc[fm][fn][r]);
      *(US4*)(W2T + (b * 512 + c) * 512 + h * 64 + d0) = p;
    }
}

// ---------------- K3: final GEMM  out = qhat @ W2_b + bias ----------------
__global__ __launch_bounds__(256, 2)
void k_out_gemm(const char* __restrict__ qhat, const char* __restrict__ W2T,
                const float* __restrict__ bproj, float* __restrict__ outp) {
  __shared__ __align__(16) char lds[32768];
  const int bx = blockIdx.x;
  const int tM = bx & 127, tN = bx >> 7;  // 128 M-tiles, 4 N-tiles
  const int b = tM >> 5;
  fx4 acc[4][4];
  const fx4 z4 = {0.f, 0.f, 0.f, 0.f};
  #pragma unroll
  for (int i = 0; i < 4; ++i)
    #pragma unroll
    for (int j = 0; j < 4; ++j) acc[i][j] = z4;

  gemm_core(qhat + tM * 131072, W2T + b * 524288 + tN * 131072, lds, lds + 16384, acc);

  const int t = threadIdx.x, w = t >> 6, l = t & 63;
  const int wm = w >> 1, wn = w & 1;
  const int m0 = tM * 128 + wm * 64;
  const int c0 = tN * 128 + wn * 64;
  #pragma unroll
  for (int fm = 0; fm < 4; ++fm)
    #pragma unroll
    for (int fn = 0; fn < 4; ++fn) {
      int c = c0 + fn * 16 + (l & 15);
      float bp = bproj[c];
      #pragma unroll
      for (int r = 0; r < 4; ++r) {
        int m = m0 + fm * 16 + ((l >> 4) * 4) + r;
        outp[m * 512 + c] = acc[fm][fn][r] + bp;
      }
    }
}

extern "C" void kernel_launch(void* const* d_in, const int* in_sizes, int n_in,
                              void* d_out, int out_size, void* d_ws, size_t ws_size,
                              hipStream_t stream) {
  (void)in_sizes; (void)n_in; (void)out_size;
  const float* x     = (const float*)d_in[0];
  const float* wqkv  = (const float*)d_in[1];
  const float* wproj = (const float*)d_in[2];
  const float* bproj = (const float*)d_in[3];
  float* outp = (float*)d_out;
  char* ws = (char*)d_ws;

  char* xb   = ws;                 // 16384*512*2       = 16,777,216
  char* wqT  = ws + 16777216;      // 1536*512*2        =  1,572,864
  char* wpT  = ws + 18350080;      // 512*512*2         =    524,288
  char* qhat = ws + 18874368;      // 16384*512*2       = 16,777,216
  char* ctxp = ws + 35651584;      // 32*32*4096*4      = 16,777,216
  char* zp   = ws + 52428800;      // 32*32*64*4        =    262,144
  char* w2t  = ws + 52690944;      // 4*512*512*2       =  2,097,152  (end 54,788,096)
  if (ws_size < 54788096) return;

  k_conv<<<8192, 256, 0, stream>>>(x, (u16*)xb, 2097152);
  k_transpose<<<192, 256, 0, stream>>>(wqkv, (u16*)wqT, 512, 1536, 8, 1);
  k_transpose<<<64, 256, 0, stream>>>(wproj, (u16*)wpT, 512, 512, 8, 0);
  k_qkv_gemm<<<1536, 256, 0, stream>>>(xb, wqT, (u16*)qhat, (float*)ctxp, (float*)zp);
  k_w2<<<32, 256, 0, stream>>>((const float*)ctxp, (const float*)zp, (const u16*)wpT, (u16*)w2t);
  k_out_gemm<<<512, 256, 0, stream>>>(qhat, w2t, bproj, outp);
}

// Round 8
// 79.331 us; speedup vs baseline: 1.4408x; 1.1309x over previous
//
#include <hip/hip_runtime.h>
#include <hip/hip_bf16.h>

typedef unsigned short u16;
typedef __attribute__((ext_vector_type(8))) short bhalf8;
typedef __attribute__((ext_vector_type(4))) float fx4;

struct __align__(8) US4 { u16 v[4]; };

__device__ __forceinline__ u16 f2bf(float x) {
  union { float f; unsigned int u; } c; c.f = x;
  unsigned int r = c.u + 0x7FFFu + ((c.u >> 16) & 1u);
  return (u16)(r >> 16);
}

__device__ __forceinline__ float bf2f(u16 v) {
  union { unsigned int u; float f; } c; c.u = ((unsigned int)v) << 16;
  return c.f;
}

__device__ __forceinline__ void gload16(const void* g, void* l) {
  __builtin_amdgcn_global_load_lds((const __attribute__((address_space(1))) void*)g,
                                   (__attribute__((address_space(3))) void*)l,
                                   16, 0, 0);
}

#define MFMA16(a, b, c) __builtin_amdgcn_mfma_f32_16x16x32_bf16((a), (b), (c), 0, 0, 0)

// ---------------- K0: merged prep — x conv (blocks 0..8191), wqkv transpose
// (8192..8383, remap), wproj transpose (8384..8447) ----------------
__global__ __launch_bounds__(256)
void k_prep(const float* __restrict__ x, u16* __restrict__ xb,
            const float* __restrict__ wqkv, u16* __restrict__ wqT,
            const float* __restrict__ wproj, u16* __restrict__ wpT) {
  __shared__ float tile[64][65];
  const int bx = blockIdx.x;
  const int t = threadIdx.x;
  if (bx < 8192) {
    int i = bx * 256 + t;
    float4 v = ((const float4*)x)[i];
    US4 o;
    o.v[0] = f2bf(v.x); o.v[1] = f2bf(v.y); o.v[2] = f2bf(v.z); o.v[3] = f2bf(v.w);
    ((US4*)xb)[i] = o;
    return;
  }
  // transpose [R=512][C] f32 -> [C][512] bf16, 64x64 tiles
  const float* in; u16* out; int C, remap, bx2;
  if (bx < 8384) { in = wqkv; out = wqT; C = 1536; remap = 1; bx2 = bx - 8192; }
  else           { in = wproj; out = wpT; C = 512;  remap = 0; bx2 = bx - 8384; }
  const int rt = bx2 & 7, ct = bx2 >> 3;
  const int r0 = rt * 64, c0 = ct * 64;
  #pragma unroll
  for (int i = 0; i < 16; ++i) {
    int e = i * 256 + t;
    int rr = e >> 6, cc = e & 63;
    tile[rr][cc] = in[(r0 + rr) * C + c0 + cc];
  }
  __syncthreads();
  #pragma unroll
  for (int i = 0; i < 16; ++i) {
    int e = i * 256 + t;
    int rr = e >> 6, cc = e & 63;
    int orow = c0 + rr;
    if (remap && orow >= 512) {
      int region = (orow - 512) >> 9;       // 0=K, 1=V
      int within = (orow - 512) & 511;
      int h = within >> 6;
      orow = 512 + h * 128 + region * 64 + (within & 63);
    }
    out[orow * 512 + r0 + cc] = f2bf(tile[cc][rr]);
  }
}

// ---------------- shared 128x128 GEMM mainloop (K=512, both operand row strides = 1024B) ----------------
__device__ __forceinline__ void gemm_core(const char* Ab, const char* Bb,
                                          char* As, char* Bs, fx4 acc[4][4]) {
  const int t = threadIdx.x;
  const int w = t >> 6, l = t & 63;
  const int wm = w >> 1, wn = w & 1;
  #pragma unroll 1
  for (int kt = 0; kt < 8; ++kt) {
    __syncthreads();
    const int kb = kt * 128;
    #pragma unroll
    for (int j = 0; j < 4; ++j) {
      int off = ((j * 4 + w) * 64 + l) * 16;     // byte offset in 16KB tile
      int row = off >> 7;
      int colb = off & 127;
      int scol = colb ^ ((row & 7) << 4);        // pre-swizzled global source
      gload16(Ab + row * 1024 + kb + scol, As + off);
      gload16(Bb + row * 1024 + kb + scol, Bs + off);
    }
    asm volatile("s_waitcnt vmcnt(0)" ::: "memory");
    __syncthreads();
    #pragma unroll
    for (int ks = 0; ks < 2; ++ks) {
      bhalf8 af[4], bfv[4];
      const int kbyte = ks * 64 + ((l >> 4) * 16);
      #pragma unroll
      for (int f = 0; f < 4; ++f) {
        int ra = wm * 64 + f * 16 + (l & 15);
        af[f] = *(const bhalf8*)(As + ra * 128 + (kbyte ^ ((ra & 7) << 4)));
        int rb = wn * 64 + f * 16 + (l & 15);
        bfv[f] = *(const bhalf8*)(Bs + rb * 128 + (kbyte ^ ((rb & 7) << 4)));
      }
      #pragma unroll
      for (int fm = 0; fm < 4; ++fm)
        #pragma unroll
        for (int fn = 0; fn < 4; ++fn)
          acc[fm][fn] = MFMA16(af[fm], bfv[fn], acc[fm][fn]);
    }
  }
}

// ---------------- K1: qkv GEMM + fused q-softmax / k-exp / per-block context partials ----------------
// tN 0..3: Q cols. tN 4..11: head h=tN-4, tile cols 0..63 = K-head-h, 64..127 = V-head-h
__global__ __launch_bounds__(256, 2)
void k_qkv_gemm(const char* __restrict__ xb, const char* __restrict__ wqT,
                u16* __restrict__ qhat, u16* __restrict__ ctx_part,
                float* __restrict__ z_part) {
  __shared__ __align__(16) char lds[32768];
  const int bx = blockIdx.x;
  const int tM = bx & 127, tN = bx >> 7;  // 128 M-tiles, 12 N-tiles
  fx4 acc[4][4];
  const fx4 z4 = {0.f, 0.f, 0.f, 0.f};
  #pragma unroll
  for (int i = 0; i < 4; ++i)
    #pragma unroll
    for (int j = 0; j < 4; ++j) acc[i][j] = z4;

  gemm_core(xb + tM * 131072, wqT + tN * 131072, lds, lds + 16384, acc);

  const int t = threadIdx.x, w = t >> 6, l = t & 63;
  const int wm = w >> 1, wn = w & 1;
  const int m0 = tM * 128 + wm * 64;
  const int c0 = tN * 128 + wn * 64;

  if (tN < 4) {
    // q: softmax over the 64 head-dim cols (exactly this wave's col span)
    #pragma unroll
    for (int fm = 0; fm < 4; ++fm) {
      #pragma unroll
      for (int fn = 0; fn < 4; ++fn)
        #pragma unroll
        for (int r = 0; r < 4; ++r)
          acc[fm][fn][r] = __expf(acc[fm][fn][r]);
      fx4 s = acc[fm][0] + acc[fm][1] + acc[fm][2] + acc[fm][3];
      fx4 inv;
      #pragma unroll
      for (int r = 0; r < 4; ++r) {
        float sv = s[r];
        sv += __shfl_xor(sv, 1, 64);
        sv += __shfl_xor(sv, 2, 64);
        sv += __shfl_xor(sv, 4, 64);
        sv += __shfl_xor(sv, 8, 64);
        inv[r] = 1.0f / sv;
      }
      #pragma unroll
      for (int fn = 0; fn < 4; ++fn)
        #pragma unroll
        for (int r = 0; r < 4; ++r) {
          int m = m0 + fm * 16 + ((l >> 4) * 4) + r;
          int c = c0 + fn * 16 + (l & 15);
          qhat[m * 512 + c] = f2bf(acc[fm][fn][r] * inv[r]);
        }
    }
  } else {
    const int h = tN - 4;
    const int b = tM >> 5;
    const int mt = tM & 31;
    const int bh = b * 8 + h;
    char* ktb = lds;            // 64 x 128 bf16, swizzled, 16KB
    char* vtb = lds + 16384;    // 64 x 128 bf16, swizzled, 16KB
    __syncthreads();            // staging LDS free now
    {
      char* dstb = (wn == 0) ? ktb : vtb;
      const bool isK = (wn == 0);
      #pragma unroll
      for (int fm = 0; fm < 4; ++fm)
        #pragma unroll
        for (int fn = 0; fn < 4; ++fn) {
          int d = fn * 16 + (l & 15);
          int n0 = wm * 64 + fm * 16 + ((l >> 4) * 4);
          US4 p;
          #pragma unroll
          for (int r = 0; r < 4; ++r) {
            float v = acc[fm][fn][r];
            if (isK) { float tt = v > 0.f ? v + 1.f : __expf(v); v = __expf(tt); }
            p.v[r] = f2bf(v);
          }
          *(US4*)(dstb + d * 256 + ((2 * n0) ^ ((d & 7) << 4))) = p;
        }
    }
    __syncthreads();
    // ctx[d][e] = sum_n khat[d][n]*v[e][n]; wave w owns d-rows [w*16, w*16+16)
    fx4 cacc[4]; fx4 zacc = z4;
    #pragma unroll
    for (int fn = 0; fn < 4; ++fn) cacc[fn] = z4;
    bhalf8 ones;
    #pragma unroll
    for (int i = 0; i < 8; ++i) ones[i] = (short)0x3F80;  // bf16 1.0
    #pragma unroll
    for (int kk = 0; kk < 4; ++kk) {
      int nbyte = kk * 64 + ((l >> 4) * 16);
      int d = w * 16 + (l & 15);
      bhalf8 a = *(const bhalf8*)(ktb + d * 256 + (nbyte ^ ((d & 7) << 4)));
      #pragma unroll
      for (int fn = 0; fn < 4; ++fn) {
        int e = fn * 16 + (l & 15);
        bhalf8 bv = *(const bhalf8*)(vtb + e * 256 + (nbyte ^ ((e & 7) << 4)));
        cacc[fn] = MFMA16(a, bv, cacc[fn]);
      }
      zacc = MFMA16(a, ones, zacc);
    }
    u16* cp = ctx_part + (bh * 32 + mt) * 4096;
    #pragma unroll
    for (int fn = 0; fn < 4; ++fn)
      #pragma unroll
      for (int r = 0; r < 4; ++r) {
        int d = w * 16 + ((l >> 4) * 4) + r;
        int e = fn * 16 + (l & 15);
        cp[d * 64 + e] = f2bf(cacc[fn][r]);
      }
    if ((l & 15) == 0) {
      #pragma unroll
      for (int r = 0; r < 4; ++r)
        z_part[(bh * 32 + mt) * 64 + w * 16 + ((l >> 4) * 4) + r] = zacc[r];
    }
  }
}

// ---------------- K2: reduce bf16 ctx partials over the 32 M-blocks (f32 accum) ----------------
__global__ __launch_bounds__(256)
void k_reduce(const u16* __restrict__ ctx_part, float* __restrict__ ctx32) {
  const int bid = blockIdx.x;           // 128 = 32 bh x 4 quarters
  const int bh = bid >> 2;
  const int idx0 = (bid & 3) * 1024 + threadIdx.x * 4;
  float s0 = 0.f, s1 = 0.f, s2 = 0.f, s3 = 0.f;
  #pragma unroll
  for (int mt = 0; mt < 32; ++mt) {
    US4 p = *(const US4*)(ctx_part + (bh * 32 + mt) * 4096 + idx0);
    s0 += bf2f(p.v[0]); s1 += bf2f(p.v[1]); s2 += bf2f(p.v[2]); s3 += bf2f(p.v[3]);
  }
  float4 o; o.x = s0; o.y = s1; o.z = s2; o.w = s3;
  *(float4*)(ctx32 + bh * 4096 + idx0) = o;
}

// ---------------- K3: W2T[b][c][hd] = sum_e (ctx[d][e]/Z[d]) * wp[h*64+e][c]  (bf16 MFMA) ----------------
__global__ __launch_bounds__(256, 1)
void k_w2(const float* __restrict__ ctx32, const float* __restrict__ z_part,
          const u16* __restrict__ wpT, u16* __restrict__ W2T) {
  const int bh = blockIdx.x;            // 32
  const int b = bh >> 3, h = bh & 7;
  __shared__ float zinv[64];
  __shared__ __align__(16) u16 alds[64][72];
  const int t = threadIdx.x;
  if (t < 64) {
    float zs = 0.f;
    #pragma unroll
    for (int mt = 0; mt < 32; ++mt) zs += z_part[(bh * 32 + mt) * 64 + t];
    zinv[t] = 1.0f / zs;
  }
  __syncthreads();
  #pragma unroll
  for (int i = 0; i < 16; ++i) {
    int idx = i * 256 + t;
    int d = idx >> 6, e = idx & 63;
    alds[d][e] = f2bf(ctx32[bh * 4096 + idx] * zinv[d]);
  }
  __syncthreads();
  const int w = t >> 6, l = t & 63;
  fx4 acc[4][8];
  const fx4 z4 = {0.f, 0.f, 0.f, 0.f};
  #pragma unroll
  for (int i = 0; i < 4; ++i)
    #pragma unroll
    for (int j = 0; j < 8; ++j) acc[i][j] = z4;
  #pragma unroll
  for (int ks = 0; ks < 2; ++ks) {
    bhalf8 af[4];
    #pragma unroll
    for (int fm = 0; fm < 4; ++fm) {
      int row = fm * 16 + (l & 15);
      af[fm] = *(const bhalf8*)((const char*)alds + row * 144 + ks * 64 + ((l >> 4) * 16));
    }
    #pragma unroll
    for (int fn = 0; fn < 8; ++fn) {
      int c = w * 128 + fn * 16 + (l & 15);
      bhalf8 bv = *(const bhalf8*)(wpT + c * 512 + h * 64 + ks * 32 + ((l >> 4) * 8));
      #pragma unroll
      for (int fm = 0; fm < 4; ++fm)
        acc[fm][fn] = MFMA16(af[fm], bv, acc[fm][fn]);
    }
  }
  #pragma unroll
  for (int fm = 0; fm < 4; ++fm)
    #pragma unroll
    for (int fn = 0; fn < 8; ++fn) {
      int c = w * 128 + fn * 16 + (l & 15);
      int d0 = fm * 16 + ((l >> 4) * 4);
      US4 p;
      #pragma unroll
      for (int r = 0; r < 4; ++r) p.v[r] = f2bf(acc[fm][fn][r]);
      *(US4*)(W2T + (b * 512 + c) * 512 + h * 64 + d0) = p;
    }
}

// ---------------- K4: final GEMM  out = qhat @ W2_b + bias ----------------
__global__ __launch_bounds__(256, 2)
void k_out_gemm(const char* __restrict__ qhat, const char* __restrict__ W2T,
                const float* __restrict__ bproj, float* __restrict__ outp) {
  __shared__ __align__(16) char lds[32768];
  const int bx = blockIdx.x;
  const int tM = bx & 127, tN = bx >> 7;  // 128 M-tiles, 4 N-tiles
  const int b = tM >> 5;
  fx4 acc[4][4];
  const fx4 z4 = {0.f, 0.f, 0.f, 0.f};
  #pragma unroll
  for (int i = 0; i < 4; ++i)
    #pragma unroll
    for (int j = 0; j < 4; ++j) acc[i][j] = z4;

  gemm_core(qhat + tM * 131072, W2T + b * 524288 + tN * 131072, lds, lds + 16384, acc);

  const int t = threadIdx.x, w = t >> 6, l = t & 63;
  const int wm = w >> 1, wn = w & 1;
  const int m0 = tM * 128 + wm * 64;
  const int c0 = tN * 128 + wn * 64;
  #pragma unroll
  for (int fm = 0; fm < 4; ++fm)
    #pragma unroll
    for (int fn = 0; fn < 4; ++fn) {
      int c = c0 + fn * 16 + (l & 15);
      float bp = bproj[c];
      #pragma unroll
      for (int r = 0; r < 4; ++r) {
        int m = m0 + fm * 16 + ((l >> 4) * 4) + r;
        outp[m * 512 + c] = acc[fm][fn][r] + bp;
      }
    }
}

extern "C" void kernel_launch(void* const* d_in, const int* in_sizes, int n_in,
                              void* d_out, int out_size, void* d_ws, size_t ws_size,
                              hipStream_t stream) {
  (void)in_sizes; (void)n_in; (void)out_size;
  const float* x     = (const float*)d_in[0];
  const float* wqkv  = (const float*)d_in[1];
  const float* wproj = (const float*)d_in[2];
  const float* bproj = (const float*)d_in[3];
  float* outp = (float*)d_out;
  char* ws = (char*)d_ws;

  char* xb   = ws;                 // 16384*512*2       = 16,777,216
  char* wqT  = ws + 16777216;      // 1536*512*2        =  1,572,864
  char* wpT  = ws + 18350080;      // 512*512*2         =    524,288
  char* qhat = ws + 18874368;      // 16384*512*2       = 16,777,216
  char* ctxp = ws + 35651584;      // 32*32*4096*2 bf16 =  8,388,608
  char* zp   = ws + 44040192;      // 32*32*64*4        =    262,144
  char* ctx32= ws + 44302336;      // 32*4096*4         =    524,288
  char* w2t  = ws + 44826624;      // 4*512*512*2       =  2,097,152  (end 46,923,776)
  if (ws_size < 46923776) return;

  k_prep<<<8448, 256, 0, stream>>>(x, (u16*)xb, wqkv, (u16*)wqT, wproj, (u16*)wpT);
  k_qkv_gemm<<<1536, 256, 0, stream>>>(xb, wqT, (u16*)qhat, (u16*)ctxp, (float*)zp);
  k_reduce<<<128, 256, 0, stream>>>((const u16*)ctxp, (float*)ctx32);
  k_w2<<<32, 256, 0, stream>>>((const float*)ctx32, (const float*)zp, (const u16*)wpT, (u16*)w2t);
  k_out_gemm<<<512, 256, 0, stream>>>(qhat, w2t, bproj, outp);
}